// Round 27
// baseline (96.571 us; speedup 1.0000x reference)
//
#include <hip/hip_runtime.h>
#include <hip/hip_bf16.h>
#include <math.h>

#define Bb 512
#define Tt 256
#define Cc 384
#define Hh 64

#define WCH 12288  // chunk-major W: 192*64 shorts per k-chunk

// LDS (shorts) — full 160 KiB. X0/X1 are DEDICATED (b1 prefetch lands there
// while C(b0) reads K/VT/Q). W dbuf aliases K/VT front (phase-disjoint).
#define OFF_X0 0                   // [256][32] fp32 = 16384 shorts
#define OFF_X1 16384
#define OFF_K  32768               // [256][64] bf16
#define OFF_VT 49152               // [64][256] bf16
#define OFF_Q  65536               // [256][64] bf16
#define LDST   81920               // shorts = 163,840 B = 160 KiB exactly
#define OFF_W0 32768               // alias K
#define OFF_W1 45056               // ends 57,344 <= 65,536 (inside K+VT)

typedef __attribute__((ext_vector_type(8))) short short8;
typedef __attribute__((ext_vector_type(4))) short short4_;
typedef __attribute__((ext_vector_type(4))) float float4_;

static __device__ __forceinline__ unsigned short f2bf(float f) {
  __hip_bfloat16 h = __float2bfloat16(f);
  return *reinterpret_cast<unsigned short*>(&h);
}

// XOR swizzles: 8-short (16B) slots, slot ^= row&7 (bijective per 8-slot group)
static __device__ __forceinline__ int swz64(int row, int col) {
  return row * 64 + ((((col >> 3) ^ (row & 7)) << 3) | (col & 7));
}
static __device__ __forceinline__ int swz256(int row, int col) {
  int c8 = col >> 3;
  return row * 256 + ((((c8 & ~7) | ((c8 & 7) ^ (row & 7))) << 3) | (col & 7));
}

// global -> LDS direct (width 16B), zero registers held
#define GLOAD_LDS(g, l)                                                        \
  __builtin_amdgcn_global_load_lds(                                            \
      (const __attribute__((address_space(1))) unsigned int*)(const void*)(g), \
      (__attribute__((address_space(3))) unsigned int*)(void*)(l), 16, 0, 0)

// ---------------- kernel 0: pack W chunk-major bf16: wt[ks][192][64] ----------------
__global__ __launch_bounds__(256) void wtrans_kernel(
    const float* __restrict__ wq, const float* __restrict__ wk,
    const float* __restrict__ wv, unsigned short* __restrict__ wt) {
  __shared__ float tl[384 * 8];
  const int blk = blockIdx.x;
  const int wsel = blk >> 3, n0 = (blk & 7) * 8;
  const float* w = (wsel == 0) ? wq : (wsel == 1) ? wk : wv;
  const int t = threadIdx.x;
#pragma unroll
  for (int i = 0; i < 3; i++) {
    int id = i * 256 + t;
    int row = id >> 1, sg = id & 1;
    float4_ v = *(const float4_*)(w + row * Hh + n0 + sg * 4);
    *(float4_*)(&tl[row * 8 + sg * 4]) = v;
  }
  __syncthreads();
#pragma unroll
  for (int i = 0; i < 12; i++) {
    int id = i * 256 + t;
    int n = id / 384, k = id % 384;
    int row = wsel * 64 + n0 + n;
    wt[(size_t)(k >> 6) * WCH + row * 64 + (k & 63)] = f2bf(tl[k * 8 + n]);
  }
}

// ---------------- fused kernel: 2 batches/block; cross-batch x prefetch ----------------
// R26 phases (1024t, gload_lds x, counted vmcnt, QT-balanced C) in a 2-batch
// loop. After phase B of batch 0: fire batch 1's x chunks 0/1 (zero-register
// DMA into DEDICATED X regions) -> they stream under phase C's shadow. At
// 1024t phase C uses ~70 VGPR of the 128 cap (acc=48), so unlike R20@512t
// there is real headroom and nothing is held in registers across phases.
__global__ __launch_bounds__(1024, 1) void fused_kernel(
    const float* __restrict__ x, const unsigned short* __restrict__ wt,
    float* __restrict__ out) {
  __shared__ unsigned short lds[LDST];
  unsigned short* k_lds  = lds + OFF_K;
  unsigned short* vt_lds = lds + OFF_VT;
  unsigned short* q_lds  = lds + OFF_Q;

  const int t = threadIdx.x;
  const int wid = t >> 6, lane = t & 63;
  const int fr = lane & 15, fg = lane >> 4;
  const float SC  = 0.05103103630798288f;   // 384^-0.5
  const float L2E = 1.4426950408889634f;

  // per-lane staging geometry (own rows [wid*16, wid*16+16))
  const int srow_sub = lane >> 3;                   // 0..7 row-in-group
  const int sslot    = (lane & 7) ^ (srow_sub & 7); // pre-swizzled global slot

  // prologue: stage batch-0 x chunks 0,1
  {
    const float* xb0 = x + (size_t)(blockIdx.x * 2) * Tt * Cc;
#pragma unroll
    for (int cc = 0; cc < 2; cc++) {
      unsigned short* xd = lds + (cc ? OFF_X1 : OFF_X0);
#pragma unroll
      for (int i = 0; i < 2; i++) {
        int row = wid * 16 + i * 8 + srow_sub;
        GLOAD_LDS(xb0 + (size_t)row * Cc + cc * 32 + sslot * 4,
                  xd + (wid * 16 + i * 8) * 64);
      }
    }
  }

#pragma unroll 1
  for (int bi = 0; bi < 2; bi++) {
    const int b = blockIdx.x * 2 + bi;
    const float* xb = x + (size_t)b * Tt * Cc;

    // ================= phase A: QKV = x[b] @ W =================
    float4_ acc[12];
#pragma unroll
    for (int j = 0; j < 12; j++) acc[j] = (float4_)0.f;

    short4_ wv[3];
#pragma unroll
    for (int i = 0; i < 3; i++) {
      int id = t + i * 1024;
      wv[i] = *(const short4_*)(wt + (size_t)id * 4);
    }

#pragma unroll
    for (int ks = 0; ks < 6; ks++) {
      unsigned short* wb = lds + ((ks & 1) ? OFF_W1 : OFF_W0);
      // store W chunk ks, swizzled (compiler vmcnt-waits on wv)
#pragma unroll
      for (int i = 0; i < 3; i++) {
        int id = t + i * 1024;
        int row = id >> 4, sg = id & 15;
        *(short4_*)(&wb[swz64(row, sg * 4)]) = wv[i];
      }
      // issue W chunk ks+1 loads
      if (ks < 5) {
#pragma unroll
        for (int i = 0; i < 3; i++) {
          int id = t + i * 1024;
          wv[i] = *(const short4_*)(wt + (size_t)(ks + 1) * WCH + (size_t)id * 4);
        }
      }
      // ONE barrier per W chunk: lgkm drained; vm loads stay in flight
      asm volatile("s_waitcnt lgkmcnt(0)" ::: "memory");
      __builtin_amdgcn_s_barrier();
      __builtin_amdgcn_sched_barrier(0);

#pragma unroll
      for (int kk = 0; kk < 2; kk++) {
        const int c = 2 * ks + kk;   // K=32 x-chunk index
        // counted wait: steady queue = [x(c):2, x(c+1):2, W(ks+1):3]
        if (ks < 5)       { asm volatile("s_waitcnt vmcnt(5)" ::: "memory"); }
        else if (kk == 0) { asm volatile("s_waitcnt vmcnt(2)" ::: "memory"); }
        else              { asm volatile("s_waitcnt vmcnt(0)" ::: "memory"); }
        __builtin_amdgcn_sched_barrier(0);
        // consume x(c) from LDS (own rows; swizzled slots -> <=2-way banks)
        const float* xf = (const float*)(lds + ((c & 1) ? OFF_X1 : OFF_X0));
        short8 af;
        {
          int row = wid * 16 + fr;
          int s0 = (fg * 2) ^ (fr & 7);
          int s1 = (fg * 2 + 1) ^ (fr & 7);
          float4_ v0 = *(const float4_*)(&xf[row * 32 + s0 * 4]);
          float4_ v1 = *(const float4_*)(&xf[row * 32 + s1 * 4]);
#pragma unroll
          for (int j = 0; j < 4; j++) {
            af[j]     = (short)f2bf(v0[j]);
            af[4 + j] = (short)f2bf(v1[j]);
          }
        }
        __builtin_amdgcn_sched_barrier(0);   // ds_reads complete before re-stage
        // re-stage chunk c+2 into the buffer just consumed (fire-and-forget)
        if (c + 2 < 12) {
          unsigned short* xd = lds + ((c & 1) ? OFF_X1 : OFF_X0);
#pragma unroll
          for (int i = 0; i < 2; i++) {
            int row = wid * 16 + i * 8 + srow_sub;
            GLOAD_LDS(xb + (size_t)row * Cc + (c + 2) * 32 + sslot * 4,
                      xd + (wid * 16 + i * 8) * 64);
          }
        }
        // MFMAs for this K=32 half
#pragma unroll
        for (int ni = 0; ni < 12; ni++) {
          short8 bf = *(const short8*)(&wb[swz64(ni * 16 + fr, kk * 32 + fg * 8)]);
          acc[ni] = __builtin_amdgcn_mfma_f32_16x16x32_bf16(af, bf, acc[ni], 0, 0, 0);
        }
      }
    }
    __syncthreads();   // end phase A: all LDS reads done before aliased scatter

    // ================= phase B: scatter Q/K/V (swizzled writes) =================
    // acc D-layout: row = wid*16 + fg*4 + r, col = ni*16 + fr
    {
      int row0 = wid * 16 + fg * 4;
#pragma unroll
      for (int ni = 0; ni < 12; ni++) {
        int col = ni * 16 + fr;
        if (ni >= 8) {                      // V -> V^T [h][seq]
          short4_ pk;
#pragma unroll
          for (int r = 0; r < 4; r++) pk[r] = (short)f2bf(acc[ni][r]);
          *(short4_*)(&vt_lds[swz256(col - 128, row0)]) = pk;
        } else if (ni < 4) {                // Q -> [seq][h]
#pragma unroll
          for (int r = 0; r < 4; r++)
            q_lds[swz64(row0 + r, col)] = f2bf(acc[ni][r]);
        } else {                            // K -> [seq][h]
#pragma unroll
          for (int r = 0; r < 4; r++)
            k_lds[swz64(row0 + r, col - 64)] = f2bf(acc[ni][r]);
        }
      }
    }

    // cross-batch prefetch: fire batch bi+1's x chunks 0,1 (zero registers)
    // into the dedicated X regions; they stream under phase C's shadow.
    if (bi == 0) {
      const float* xb1 = x + (size_t)(b + 1) * Tt * Cc;
#pragma unroll
      for (int cc = 0; cc < 2; cc++) {
        unsigned short* xd = lds + (cc ? OFF_X1 : OFF_X0);
#pragma unroll
        for (int i = 0; i < 2; i++) {
          int row = wid * 16 + i * 8 + srow_sub;
          GLOAD_LDS(xb1 + (size_t)row * Cc + cc * 32 + sslot * 4,
                    xd + (wid * 16 + i * 8) * 64);
        }
      }
    }

    // B-end barrier: lgkm-only (scatter visible; prefetch DMA stays in flight)
    asm volatile("s_waitcnt lgkmcnt(0)" ::: "memory");
    __builtin_amdgcn_s_barrier();
    __builtin_amdgcn_sched_barrier(0);

    // ================= phase C: causal flash attn, QT-balanced, in-reg P =================
    {
      // per-SIMD balanced tile permutation (R26): each SIMD sums to 18 kt-steps
      static const int QT[16] = {0, 1, 2, 3, 14, 15, 12, 13, 6, 7, 4, 5, 8, 9, 10, 11};
      const int qt = QT[wid];
      short8 aq0 = *(const short8*)(&q_lds[swz64(qt * 16 + fr, fg * 8)]);
      short8 aq1 = *(const short8*)(&q_lds[swz64(qt * 16 + fr, 32 + fg * 8)]);
      float4_ o[4] = {(float4_)0.f, (float4_)0.f, (float4_)0.f, (float4_)0.f};
      float m = -3.0e38f, l = 0.f;
      const int qg = qt * 16 + fr;
      const int ktmax = qt >> 1;
      short8 kf0 = *(const short8*)(&k_lds[swz64(fr, fg * 8)]);
      short8 kf1 = *(const short8*)(&k_lds[swz64(16 + fr, fg * 8)]);
      short8 kf2 = *(const short8*)(&k_lds[swz64(fr, 32 + fg * 8)]);
      short8 kf3 = *(const short8*)(&k_lds[swz64(16 + fr, 32 + fg * 8)]);
      short8 bv0 = *(const short8*)(&vt_lds[swz256(fr, fg * 8)]);
      short8 bv1 = *(const short8*)(&vt_lds[swz256(16 + fr, fg * 8)]);
      short8 bv2 = *(const short8*)(&vt_lds[swz256(32 + fr, fg * 8)]);
      short8 bv3 = *(const short8*)(&vt_lds[swz256(48 + fr, fg * 8)]);
      for (int kt = 0; kt <= ktmax; kt++) {
        float4_ s0 = (float4_)0.f, s1 = (float4_)0.f;
        s0 = __builtin_amdgcn_mfma_f32_16x16x32_bf16(kf0, aq0, s0, 0, 0, 0);
        s1 = __builtin_amdgcn_mfma_f32_16x16x32_bf16(kf1, aq0, s1, 0, 0, 0);
        s0 = __builtin_amdgcn_mfma_f32_16x16x32_bf16(kf2, aq1, s0, 0, 0, 0);
        s1 = __builtin_amdgcn_mfma_f32_16x16x32_bf16(kf3, aq1, s1, 0, 0, 0);
        if (kt < ktmax) {
          int kb = (kt + 1) * 32;
          kf0 = *(const short8*)(&k_lds[swz64(kb + fr, fg * 8)]);
          kf1 = *(const short8*)(&k_lds[swz64(kb + 16 + fr, fg * 8)]);
          kf2 = *(const short8*)(&k_lds[swz64(kb + fr, 32 + fg * 8)]);
          kf3 = *(const short8*)(&k_lds[swz64(kb + 16 + fr, 32 + fg * 8)]);
        }
        bool edge = (kt == ktmax);
        float vs[8];
#pragma unroll
        for (int r = 0; r < 4; r++) {
          int kg0 = kt * 32 + fg * 4 + r;
          float a0 = s0[r] * SC, a1 = s1[r] * SC;
          if (edge && kg0 > qg)      a0 = -3.0e38f;
          if (edge && kg0 + 16 > qg) a1 = -3.0e38f;
          vs[r] = a0; vs[4 + r] = a1;
        }
        float mx = fmaxf(fmaxf(fmaxf(vs[0], vs[1]), fmaxf(vs[2], vs[3])),
                         fmaxf(fmaxf(vs[4], vs[5]), fmaxf(vs[6], vs[7])));
        mx = fmaxf(mx, __shfl_xor(mx, 16));
        mx = fmaxf(mx, __shfl_xor(mx, 32));
        if (!__all(mx - m <= 8.0f)) {   // defer-rescale (T13, THR=8)
          float mn = fmaxf(m, mx);
          float scal = exp2f((m - mn) * L2E);
          l *= scal;
#pragma unroll
          for (int nt = 0; nt < 4; nt++) o[nt] *= scal;
          m = mn;
        }
        float p[8]; float ps = 0.f;
#pragma unroll
        for (int j = 0; j < 8; j++) { p[j] = exp2f((vs[j] - m) * L2E); ps += p[j]; }
        ps += __shfl_xor(ps, 16);
        ps += __shfl_xor(ps, 32);
        l += ps;

        // ---- in-register P redistribution (R18-verified) ----
        unsigned a0u, a1u, a2u, a3u;
        asm("v_cvt_pk_bf16_f32 %0, %1, %2" : "=v"(a0u) : "v"(p[0]), "v"(p[1]));
        asm("v_cvt_pk_bf16_f32 %0, %1, %2" : "=v"(a1u) : "v"(p[2]), "v"(p[3]));
        asm("v_cvt_pk_bf16_f32 %0, %1, %2" : "=v"(a2u) : "v"(p[4]), "v"(p[5]));
        asm("v_cvt_pk_bf16_f32 %0, %1, %2" : "=v"(a3u) : "v"(p[6]), "v"(p[7]));
        unsigned b0u = __shfl_xor((int)a0u, 16), b1u = __shfl_xor((int)a1u, 16);
        unsigned c0u = __shfl_xor((int)a2u, 16), c1u = __shfl_xor((int)a3u, 16);
        const bool oddg = (fg & 1);
        unsigned s0u = oddg ? c0u : a0u;
        unsigned s1u = oddg ? c1u : a1u;
        unsigned s2u = oddg ? a2u : b0u;
        unsigned s3u = oddg ? a3u : b1u;
        unsigned r0u = __shfl_xor((int)s0u, 48), r1u = __shfl_xor((int)s1u, 48);
        unsigned r2u = __shfl_xor((int)s2u, 48), r3u = __shfl_xor((int)s3u, 48);
        const bool midg = (fg == 1) || (fg == 2);
        union { unsigned u[4]; short8 s; } pbv;
        pbv.u[0] = midg ? r0u : s0u;
        pbv.u[1] = midg ? r1u : s1u;
        pbv.u[2] = midg ? r2u : s2u;
        pbv.u[3] = midg ? r3u : s3u;
        short8 pb = pbv.s;
        o[0] = __builtin_amdgcn_mfma_f32_16x16x32_bf16(bv0, pb, o[0], 0, 0, 0);
        o[1] = __builtin_amdgcn_mfma_f32_16x16x32_bf16(bv1, pb, o[1], 0, 0, 0);
        o[2] = __builtin_amdgcn_mfma_f32_16x16x32_bf16(bv2, pb, o[2], 0, 0, 0);
        o[3] = __builtin_amdgcn_mfma_f32_16x16x32_bf16(bv3, pb, o[3], 0, 0, 0);
        if (kt < ktmax) {
          int kb = (kt + 1) * 32;
          bv0 = *(const short8*)(&vt_lds[swz256(fr, kb + fg * 8)]);
          bv1 = *(const short8*)(&vt_lds[swz256(16 + fr, kb + fg * 8)]);
          bv2 = *(const short8*)(&vt_lds[swz256(32 + fr, kb + fg * 8)]);
          bv3 = *(const short8*)(&vt_lds[swz256(48 + fr, kb + fg * 8)]);
        }
      }
      float inv = 1.f / l;
#pragma unroll
      for (int nt = 0; nt < 4; nt++) {
        float4_ ov = o[nt] * inv;
        *(float4_*)(&out[((size_t)b * Tt + qt * 16 + fr) * Hh + nt * 16 + fg * 4]) = ov;
      }
    }

    // fence before batch 1's W stores overwrite the K/VT alias region
    if (bi == 0) {
      asm volatile("s_waitcnt lgkmcnt(0)" ::: "memory");
      __builtin_amdgcn_s_barrier();
      __builtin_amdgcn_sched_barrier(0);
    }
  }
}

extern "C" void kernel_launch(void* const* d_in, const int* in_sizes, int n_in,
                              void* d_out, int out_size, void* d_ws, size_t ws_size,
                              hipStream_t stream) {
  const float* x  = (const float*)d_in[0];
  const float* wq = (const float*)d_in[1];
  const float* wk = (const float*)d_in[2];
  const float* wv = (const float*)d_in[3];
  unsigned short* wt = (unsigned short*)d_ws;   // 6 chunks x 192*64 bf16
  float* out = (float*)d_out;

  hipLaunchKernelGGL(wtrans_kernel, dim3(24),  dim3(256),  0, stream, wq, wk, wv, wt);
  hipLaunchKernelGGL(fused_kernel,  dim3(256), dim3(1024), 0, stream, x, wt, out);
}

// Round 28
// 60.453 us; speedup vs baseline: 1.5974x; 1.5974x over previous
//
#include <hip/hip_runtime.h>
#include <hip/hip_bf16.h>
#include <math.h>

#define Bb 512
#define Tt 256
#define Cc 384
#define Hh 64

#define WCH 12288  // chunk-major W: 192*64 shorts per k-chunk

// LDS (shorts). Phase A: x double buffer (K=32 fp32 chunks via global_load_lds)
// + W double buffer. Phase B/C aliases (temporally disjoint):
//   K [256][64]@0 | VT [64][256]@16384 | Q [256][64]@32768
// P: in-register (R18) — no LDS region.
#define OFF_X0 0                   // [256][32] fp32 = 16384 shorts
#define OFF_X1 16384
#define OFF_W0 32768               // [192][64] bf16 = 12288 shorts
#define OFF_W1 45056
#define OFF_K  0
#define OFF_VT 16384
#define OFF_Q  32768
#define LDST   57344               // shorts = 114,688 B -> 1 block/CU

typedef __attribute__((ext_vector_type(8))) short short8;
typedef __attribute__((ext_vector_type(4))) short short4_;
typedef __attribute__((ext_vector_type(4))) float float4_;

static __device__ __forceinline__ unsigned short f2bf(float f) {
  __hip_bfloat16 h = __float2bfloat16(f);
  return *reinterpret_cast<unsigned short*>(&h);
}

// XOR swizzles: 8-short (16B) slots, slot ^= row&7 (bijective per 8-slot group)
static __device__ __forceinline__ int swz64(int row, int col) {
  return row * 64 + ((((col >> 3) ^ (row & 7)) << 3) | (col & 7));
}
static __device__ __forceinline__ int swz256(int row, int col) {
  int c8 = col >> 3;
  return row * 256 + ((((c8 & ~7) | ((c8 & 7) ^ (row & 7))) << 3) | (col & 7));
}

// global -> LDS direct (width 16B), zero registers held
#define GLOAD_LDS(g, l)                                                        \
  __builtin_amdgcn_global_load_lds(                                            \
      (const __attribute__((address_space(1))) unsigned int*)(const void*)(g), \
      (__attribute__((address_space(3))) unsigned int*)(void*)(l), 16, 0, 0)

// ---------------- kernel 0: pack W chunk-major bf16: wt[ks][192][64] ----------------
__global__ __launch_bounds__(256) void wtrans_kernel(
    const float* __restrict__ wq, const float* __restrict__ wk,
    const float* __restrict__ wv, unsigned short* __restrict__ wt) {
  __shared__ float tl[384 * 8];
  const int blk = blockIdx.x;
  const int wsel = blk >> 3, n0 = (blk & 7) * 8;
  const float* w = (wsel == 0) ? wq : (wsel == 1) ? wk : wv;
  const int t = threadIdx.x;
#pragma unroll
  for (int i = 0; i < 3; i++) {
    int id = i * 256 + t;
    int row = id >> 1, sg = id & 1;
    float4_ v = *(const float4_*)(w + row * Hh + n0 + sg * 4);
    *(float4_*)(&tl[row * 8 + sg * 4]) = v;
  }
  __syncthreads();
#pragma unroll
  for (int i = 0; i < 12; i++) {
    int id = i * 256 + t;
    int n = id / 384, k = id % 384;
    int row = wsel * 64 + n0 + n;
    wt[(size_t)(k >> 6) * WCH + row * 64 + (k & 63)] = f2bf(tl[k * 8 + n]);
  }
}

// ---------------- fused kernel: per-batch QKV proj + causal flash attn ----------------
// FINAL (R26, session best 60.54us): 1024 threads (16 waves, 4 waves/SIMD);
// phase A: x via global_load_lds (counted vmcnt, pre-swizzled source), W
// reg-staged LDS double-buffer, ONE lgkm barrier per K=64 chunk; phase B:
// swizzled Q/K/V scatter; phase C: swapped-operand flash attn, in-register
// P redistribution, per-SIMD-balanced tile permutation QT (18 kt-steps/SIMD).
// Hard constraints discovered: 512-lane blocks cap at 128 arch VGPRs; ANY
// cross-phase register state or batch-loop wrapping spills (R11/13/14/20/23/27).
__global__ __launch_bounds__(1024, 1) void fused_kernel(
    const float* __restrict__ x, const unsigned short* __restrict__ wt,
    float* __restrict__ out) {
  __shared__ unsigned short lds[LDST];
  unsigned short* k_lds  = lds + OFF_K;
  unsigned short* vt_lds = lds + OFF_VT;
  unsigned short* q_lds  = lds + OFF_Q;

  const int t = threadIdx.x;
  const int wid = t >> 6, lane = t & 63;
  const int fr = lane & 15, fg = lane >> 4;
  const int b = blockIdx.x;
  const float* xb = x + (size_t)b * Tt * Cc;

  // per-lane staging geometry (own rows [wid*16, wid*16+16))
  const int srow_sub = lane >> 3;                   // 0..7 row-in-group
  const int sslot    = (lane & 7) ^ (srow_sub & 7); // pre-swizzled global slot

  // ================= phase A: QKV = x[b] @ W  (M=256, N=192, K=384) =================
  float4_ acc[12];
#pragma unroll
  for (int j = 0; j < 12; j++) acc[j] = (float4_)0.f;

  // stage x chunks 0,1 (zero registers; 2 insts per chunk per wave)
#pragma unroll
  for (int cc = 0; cc < 2; cc++) {
    unsigned short* xd = lds + (cc ? OFF_X1 : OFF_X0);
#pragma unroll
    for (int i = 0; i < 2; i++) {
      int row = wid * 16 + i * 8 + srow_sub;
      GLOAD_LDS(xb + (size_t)row * Cc + cc * 32 + sslot * 4,
                xd + (wid * 16 + i * 8) * 64);
    }
  }
  // W chunk 0 -> regs (3 x short4 per thread)
  short4_ wv[3];
#pragma unroll
  for (int i = 0; i < 3; i++) {
    int id = t + i * 1024;
    wv[i] = *(const short4_*)(wt + (size_t)id * 4);
  }

#pragma unroll
  for (int ks = 0; ks < 6; ks++) {
    unsigned short* wb = lds + ((ks & 1) ? OFF_W1 : OFF_W0);
    // store W chunk ks, swizzled (compiler waits on wv; x stages stay in flight)
#pragma unroll
    for (int i = 0; i < 3; i++) {
      int id = t + i * 1024;
      int row = id >> 4, sg = id & 15;
      *(short4_*)(&wb[swz64(row, sg * 4)]) = wv[i];
    }
    // issue W chunk ks+1 loads
    if (ks < 5) {
#pragma unroll
      for (int i = 0; i < 3; i++) {
        int id = t + i * 1024;
        wv[i] = *(const short4_*)(wt + (size_t)(ks + 1) * WCH + (size_t)id * 4);
      }
    }
    // ONE barrier per W chunk: lgkm drained; vm loads stay in flight
    asm volatile("s_waitcnt lgkmcnt(0)" ::: "memory");
    __builtin_amdgcn_s_barrier();
    __builtin_amdgcn_sched_barrier(0);

#pragma unroll
    for (int kk = 0; kk < 2; kk++) {
      const int c = 2 * ks + kk;   // K=32 x-chunk index
      // counted wait: steady state queue = [x(c):2, x(c+1):2, W(ks+1):3]
      if (ks < 5)       { asm volatile("s_waitcnt vmcnt(5)" ::: "memory"); }
      else if (kk == 0) { asm volatile("s_waitcnt vmcnt(2)" ::: "memory"); }
      else              { asm volatile("s_waitcnt vmcnt(0)" ::: "memory"); }
      __builtin_amdgcn_sched_barrier(0);
      // consume x(c) from LDS (own rows; swizzled slots -> <=2-way banks)
      const float* xf = (const float*)(lds + ((c & 1) ? OFF_X1 : OFF_X0));
      short8 af;
      {
        int row = wid * 16 + fr;
        int s0 = (fg * 2) ^ (fr & 7);
        int s1 = (fg * 2 + 1) ^ (fr & 7);
        float4_ v0 = *(const float4_*)(&xf[row * 32 + s0 * 4]);
        float4_ v1 = *(const float4_*)(&xf[row * 32 + s1 * 4]);
#pragma unroll
        for (int j = 0; j < 4; j++) {
          af[j]     = (short)f2bf(v0[j]);
          af[4 + j] = (short)f2bf(v1[j]);
        }
      }
      __builtin_amdgcn_sched_barrier(0);   // ds_reads complete before re-stage
      // re-stage chunk c+2 into the buffer just consumed (fire-and-forget)
      if (c + 2 < 12) {
        unsigned short* xd = lds + ((c & 1) ? OFF_X1 : OFF_X0);
#pragma unroll
        for (int i = 0; i < 2; i++) {
          int row = wid * 16 + i * 8 + srow_sub;
          GLOAD_LDS(xb + (size_t)row * Cc + (c + 2) * 32 + sslot * 4,
                    xd + (wid * 16 + i * 8) * 64);
        }
      }
      // MFMAs for this K=32 half
#pragma unroll
      for (int ni = 0; ni < 12; ni++) {
        short8 bf = *(const short8*)(&wb[swz64(ni * 16 + fr, kk * 32 + fg * 8)]);
        acc[ni] = __builtin_amdgcn_mfma_f32_16x16x32_bf16(af, bf, acc[ni], 0, 0, 0);
      }
    }
  }
  __syncthreads();   // end phase A: all LDS reads done before aliased scatter

  // ================= phase B: scatter Q/K/V (swizzled writes) =================
  // acc D-layout: row = wid*16 + fg*4 + r, col = ni*16 + fr
  {
    int row0 = wid * 16 + fg * 4;
#pragma unroll
    for (int ni = 0; ni < 12; ni++) {
      int col = ni * 16 + fr;
      if (ni >= 8) {                      // V -> V^T [h][seq]
        short4_ pk;
#pragma unroll
        for (int r = 0; r < 4; r++) pk[r] = (short)f2bf(acc[ni][r]);
        *(short4_*)(&vt_lds[swz256(col - 128, row0)]) = pk;
      } else if (ni < 4) {                // Q -> [seq][h]
#pragma unroll
        for (int r = 0; r < 4; r++)
          q_lds[swz64(row0 + r, col)] = f2bf(acc[ni][r]);
      } else {                            // K -> [seq][h]
#pragma unroll
        for (int r = 0; r < 4; r++)
          k_lds[swz64(row0 + r, col - 64)] = f2bf(acc[ni][r]);
      }
    }
  }
  __syncthreads();

  // ================= phase C: causal flash attn, swapped operands, in-reg P =================
  const float SC  = 0.05103103630798288f;              // 384^-0.5
  const float L2E = 1.4426950408889634f;
  {
    // tile permutation: SIMD s hosts waves {s, s+4, s+8, s+12}; QT makes each
    // SIMD's total kt-steps = 18 (len(qt) = (qt>>1)+1)
    static const int QT[16] = {0, 1, 2, 3, 14, 15, 12, 13, 6, 7, 4, 5, 8, 9, 10, 11};
    const int qt = QT[wid];
    short8 aq0 = *(const short8*)(&q_lds[swz64(qt * 16 + fr, fg * 8)]);
    short8 aq1 = *(const short8*)(&q_lds[swz64(qt * 16 + fr, 32 + fg * 8)]);
    float4_ o[4] = {(float4_)0.f, (float4_)0.f, (float4_)0.f, (float4_)0.f};
    float m = -3.0e38f, l = 0.f;
    const int qg = qt * 16 + fr;
    const int ktmax = qt >> 1;
    short8 kf0 = *(const short8*)(&k_lds[swz64(fr, fg * 8)]);
    short8 kf1 = *(const short8*)(&k_lds[swz64(16 + fr, fg * 8)]);
    short8 kf2 = *(const short8*)(&k_lds[swz64(fr, 32 + fg * 8)]);
    short8 kf3 = *(const short8*)(&k_lds[swz64(16 + fr, 32 + fg * 8)]);
    short8 bv0 = *(const short8*)(&vt_lds[swz256(fr, fg * 8)]);
    short8 bv1 = *(const short8*)(&vt_lds[swz256(16 + fr, fg * 8)]);
    short8 bv2 = *(const short8*)(&vt_lds[swz256(32 + fr, fg * 8)]);
    short8 bv3 = *(const short8*)(&vt_lds[swz256(48 + fr, fg * 8)]);
    for (int kt = 0; kt <= ktmax; kt++) {
      float4_ s0 = (float4_)0.f, s1 = (float4_)0.f;
      s0 = __builtin_amdgcn_mfma_f32_16x16x32_bf16(kf0, aq0, s0, 0, 0, 0);
      s1 = __builtin_amdgcn_mfma_f32_16x16x32_bf16(kf1, aq0, s1, 0, 0, 0);
      s0 = __builtin_amdgcn_mfma_f32_16x16x32_bf16(kf2, aq1, s0, 0, 0, 0);
      s1 = __builtin_amdgcn_mfma_f32_16x16x32_bf16(kf3, aq1, s1, 0, 0, 0);
      if (kt < ktmax) {
        int kb = (kt + 1) * 32;
        kf0 = *(const short8*)(&k_lds[swz64(kb + fr, fg * 8)]);
        kf1 = *(const short8*)(&k_lds[swz64(kb + 16 + fr, fg * 8)]);
        kf2 = *(const short8*)(&k_lds[swz64(kb + fr, 32 + fg * 8)]);
        kf3 = *(const short8*)(&k_lds[swz64(kb + 16 + fr, 32 + fg * 8)]);
      }
      bool edge = (kt == ktmax);
      float vs[8];
#pragma unroll
      for (int r = 0; r < 4; r++) {
        int kg0 = kt * 32 + fg * 4 + r;
        float a0 = s0[r] * SC, a1 = s1[r] * SC;
        if (edge && kg0 > qg)      a0 = -3.0e38f;
        if (edge && kg0 + 16 > qg) a1 = -3.0e38f;
        vs[r] = a0; vs[4 + r] = a1;
      }
      float mx = fmaxf(fmaxf(fmaxf(vs[0], vs[1]), fmaxf(vs[2], vs[3])),
                       fmaxf(fmaxf(vs[4], vs[5]), fmaxf(vs[6], vs[7])));
      mx = fmaxf(mx, __shfl_xor(mx, 16));
      mx = fmaxf(mx, __shfl_xor(mx, 32));
      if (!__all(mx - m <= 8.0f)) {   // defer-rescale (T13, THR=8)
        float mn = fmaxf(m, mx);
        float scal = exp2f((m - mn) * L2E);
        l *= scal;
#pragma unroll
        for (int nt = 0; nt < 4; nt++) o[nt] *= scal;
        m = mn;
      }
      float p[8]; float ps = 0.f;
#pragma unroll
      for (int j = 0; j < 8; j++) { p[j] = exp2f((vs[j] - m) * L2E); ps += p[j]; }
      ps += __shfl_xor(ps, 16);
      ps += __shfl_xor(ps, 32);
      l += ps;

      // ---- in-register P redistribution (R18-verified) ----
      unsigned a0u, a1u, a2u, a3u;
      asm("v_cvt_pk_bf16_f32 %0, %1, %2" : "=v"(a0u) : "v"(p[0]), "v"(p[1]));
      asm("v_cvt_pk_bf16_f32 %0, %1, %2" : "=v"(a1u) : "v"(p[2]), "v"(p[3]));
      asm("v_cvt_pk_bf16_f32 %0, %1, %2" : "=v"(a2u) : "v"(p[4]), "v"(p[5]));
      asm("v_cvt_pk_bf16_f32 %0, %1, %2" : "=v"(a3u) : "v"(p[6]), "v"(p[7]));
      unsigned b0u = __shfl_xor((int)a0u, 16), b1u = __shfl_xor((int)a1u, 16);
      unsigned c0u = __shfl_xor((int)a2u, 16), c1u = __shfl_xor((int)a3u, 16);
      const bool oddg = (fg & 1);
      unsigned s0u = oddg ? c0u : a0u;
      unsigned s1u = oddg ? c1u : a1u;
      unsigned s2u = oddg ? a2u : b0u;
      unsigned s3u = oddg ? a3u : b1u;
      unsigned r0u = __shfl_xor((int)s0u, 48), r1u = __shfl_xor((int)s1u, 48);
      unsigned r2u = __shfl_xor((int)s2u, 48), r3u = __shfl_xor((int)s3u, 48);
      const bool midg = (fg == 1) || (fg == 2);
      union { unsigned u[4]; short8 s; } pbv;
      pbv.u[0] = midg ? r0u : s0u;
      pbv.u[1] = midg ? r1u : s1u;
      pbv.u[2] = midg ? r2u : s2u;
      pbv.u[3] = midg ? r3u : s3u;
      short8 pb = pbv.s;
      o[0] = __builtin_amdgcn_mfma_f32_16x16x32_bf16(bv0, pb, o[0], 0, 0, 0);
      o[1] = __builtin_amdgcn_mfma_f32_16x16x32_bf16(bv1, pb, o[1], 0, 0, 0);
      o[2] = __builtin_amdgcn_mfma_f32_16x16x32_bf16(bv2, pb, o[2], 0, 0, 0);
      o[3] = __builtin_amdgcn_mfma_f32_16x16x32_bf16(bv3, pb, o[3], 0, 0, 0);
      if (kt < ktmax) {
        int kb = (kt + 1) * 32;
        bv0 = *(const short8*)(&vt_lds[swz256(fr, kb + fg * 8)]);
        bv1 = *(const short8*)(&vt_lds[swz256(16 + fr, kb + fg * 8)]);
        bv2 = *(const short8*)(&vt_lds[swz256(32 + fr, kb + fg * 8)]);
        bv3 = *(const short8*)(&vt_lds[swz256(48 + fr, kb + fg * 8)]);
      }
    }
    float inv = 1.f / l;
#pragma unroll
    for (int nt = 0; nt < 4; nt++) {
      float4_ ov = o[nt] * inv;
      *(float4_*)(&out[((size_t)b * Tt + qt * 16 + fr) * Hh + nt * 16 + fg * 4]) = ov;
    }
  }
}

extern "C" void kernel_launch(void* const* d_in, const int* in_sizes, int n_in,
                              void* d_out, int out_size, void* d_ws, size_t ws_size,
                              hipStream_t stream) {
  const float* x  = (const float*)d_in[0];
  const float* wq = (const float*)d_in[1];
  const float* wk = (const float*)d_in[2];
  const float* wv = (const float*)d_in[3];
  unsigned short* wt = (unsigned short*)d_ws;   // 6 chunks x 192*64 bf16
  float* out = (float*)d_out;

  hipLaunchKernelGGL(wtrans_kernel, dim3(24), dim3(256),  0, stream, wq, wk, wv, wt);
  hipLaunchKernelGGL(fused_kernel,  dim3(Bb), dim3(1024), 0, stream, x, wt, out);
}